// Round 1
// baseline (756.368 us; speedup 1.0000x reference)
//
#include <hip/hip_runtime.h>

#define H 128
#define ND 4096

__device__ __forceinline__ unsigned enc_f(float f) {
    unsigned u = __float_as_uint(f);
    return (u & 0x80000000u) ? ~u : (u | 0x80000000u);
}
__device__ __forceinline__ float dec_f(unsigned u) {
    return (u & 0x80000000u) ? __uint_as_float(u ^ 0x80000000u)
                             : __uint_as_float(~u);
}

// K1: one wave per entry (grid-stride). Coalesced float2 row load, butterfly
// reduce to the per-entry attention score; lane0 stores score + atomicMax.
__global__ void k1_scores(const float* __restrict__ ph,
                          const float* __restrict__ w_attn,
                          const int* __restrict__ prot_idx,
                          const int* __restrict__ gid,
                          float* __restrict__ scores,
                          unsigned* __restrict__ gmax, int E) {
    int lane = threadIdx.x & 63;
    int wid  = (blockIdx.x * blockDim.x + threadIdx.x) >> 6;
    int nw   = (gridDim.x * blockDim.x) >> 6;
    float2 wa = *(const float2*)(w_attn + 2 * lane);
    for (int e = wid; e < E; e += nw) {
        int p = prot_idx[e];
        float2 v = *(const float2*)(ph + (size_t)p * H + 2 * lane);
        float s = v.x * wa.x + v.y * wa.y;
        #pragma unroll
        for (int m = 32; m >= 1; m >>= 1) s += __shfl_xor(s, m, 64);
        if (lane == 0) {
            scores[e] = s;
            atomicMax(&gmax[gid[e]], enc_f(s));
        }
    }
}

// K2: per-entry exp(score - segmax), store ex, atomicAdd group denom.
__global__ void k2_exp(const float* __restrict__ scores,
                       const int* __restrict__ gid,
                       const unsigned* __restrict__ gmax,
                       float* __restrict__ ex, float* __restrict__ denom, int E) {
    int e = blockIdx.x * blockDim.x + threadIdx.x;
    if (e >= E) return;
    int g = gid[e];
    float m = dec_f(gmax[g]);
    float x = expf(scores[e] - m);
    ex[e] = x;
    atomicAdd(&denom[g], x);
}

// K2b: nonempty-group count per drug (denom > 0 iff group has entries).
__global__ void k2b_cnt(const float* __restrict__ denom,
                        const int* __restrict__ g2d,
                        int* __restrict__ dcnt, int G) {
    int g = blockIdx.x * blockDim.x + threadIdx.x;
    if (g >= G) return;
    if (denom[g] > 0.f) atomicAdd(&dcnt[g2d[g]], 1);
}

// K3: one wave per CHUNK contiguous entries. Lanes cover h = 2*lane, 2*lane+1.
// Accumulate w_e * ph row locally; flush to drug_sum on group change
// (group_ids sorted -> few flushes). Atomics straight to the drug level,
// skipping the pooled[G,H] intermediate entirely.
__global__ void k3_pool(const float* __restrict__ ph,
                        const int* __restrict__ prot_idx,
                        const int* __restrict__ gid,
                        const int* __restrict__ g2d,
                        const float* __restrict__ ex,
                        const float* __restrict__ denom,
                        float* __restrict__ dsum, int E) {
    const int CHUNK = 32;
    int lane = threadIdx.x & 63;
    int wid  = (blockIdx.x * blockDim.x + threadIdx.x) >> 6;
    int e0 = wid * CHUNK;
    if (e0 >= E) return;
    int e1 = min(e0 + CHUNK, E);
    float ax = 0.f, ay = 0.f;
    int cur_g = gid[e0];
    float inv_d = 1.0f / denom[cur_g];
    for (int e = e0; e < e1; ++e) {
        float w = ex[e] * inv_d;
        int p = prot_idx[e];
        float2 v = *(const float2*)(ph + (size_t)p * H + 2 * lane);
        ax += w * v.x;
        ay += w * v.y;
        int next_g = (e + 1 < e1) ? gid[e + 1] : -1;
        if (next_g != cur_g) {
            int d = g2d[cur_g];
            atomicAdd(&dsum[(size_t)d * H + 2 * lane], ax);
            atomicAdd(&dsum[(size_t)d * H + 2 * lane + 1], ay);
            ax = 0.f; ay = 0.f;
            cur_g = next_g;
            if (next_g >= 0) inv_d = 1.0f / denom[next_g];
        }
    }
}

// K4: one block (128 threads) per drug. fingerprint row staged in LDS,
// each thread j dots its own w_out row (float4, L1/L2-resident) + bias + ReLU.
__global__ void k4_out(const float* __restrict__ dsum,
                       const int* __restrict__ dcnt,
                       const float* __restrict__ w_out,
                       const float* __restrict__ b_out,
                       float* __restrict__ out) {
    __shared__ float fp[H];
    int d = blockIdx.x;
    int j = threadIdx.x;
    int c = dcnt[d];
    float f = 0.f;
    if (c > 0) f = dsum[(size_t)d * H + j] / (float)c;
    fp[j] = f;
    __syncthreads();
    const float4* wrow = (const float4*)(w_out + (size_t)j * H);
    const float4* fvec = (const float4*)fp;
    float acc = 0.f;
    #pragma unroll
    for (int i = 0; i < H / 4; ++i) {
        float4 w4 = wrow[i];
        float4 f4 = fvec[i];
        acc += w4.x * f4.x + w4.y * f4.y + w4.z * f4.z + w4.w * f4.w;
    }
    acc += b_out[j];
    out[(size_t)d * H + j] = fmaxf(acc, 0.f);
}

extern "C" void kernel_launch(void* const* d_in, const int* in_sizes, int n_in,
                              void* d_out, int out_size, void* d_ws, size_t ws_size,
                              hipStream_t stream) {
    const float* protein_h = (const float*)d_in[0];
    const float* w_attn    = (const float*)d_in[1];
    const float* w_out     = (const float*)d_in[2];
    const float* b_out     = (const float*)d_in[3];
    const int*   prot_idx  = (const int*)d_in[4];
    const int*   group_ids = (const int*)d_in[5];
    const int*   g2d       = (const int*)d_in[6];

    const int E = in_sizes[4];
    const int G = in_sizes[6];

    // Workspace layout (floats/uints, all 4B):
    float*    scores = (float*)d_ws;              // E
    float*    ex     = scores + E;                // E
    unsigned* gmax   = (unsigned*)(ex + E);       // G  (0 == below all encodings)
    float*    denom  = (float*)(gmax + G);        // G
    float*    dsum   = denom + G;                 // ND*H
    int*      dcnt   = (int*)(dsum + (size_t)ND * H); // ND

    // Zero the accumulator region (gmax..dcnt contiguous).
    size_t zbytes = ((size_t)G + G + (size_t)ND * H + ND) * 4;
    hipMemsetAsync(gmax, 0, zbytes, stream);

    // K1: scores + per-group max. 8192 blocks * 4 waves, grid-stride.
    k1_scores<<<8192, 256, 0, stream>>>(protein_h, w_attn, prot_idx, group_ids,
                                        scores, gmax, E);
    // K2: exp + denom.
    k2_exp<<<(E + 255) / 256, 256, 0, stream>>>(scores, group_ids, gmax, ex, denom, E);
    // K2b: per-drug nonempty-group counts.
    k2b_cnt<<<(G + 255) / 256, 256, 0, stream>>>(denom, g2d, dcnt, G);
    // K3: weighted pool -> drug_sum. One wave per 32 entries.
    int waves = (E + 31) / 32;
    int blocks3 = (waves + 3) / 4;
    k3_pool<<<blocks3, 256, 0, stream>>>(protein_h, prot_idx, group_ids, g2d,
                                         ex, denom, dsum, E);
    // K4: fingerprint + out_proj + ReLU.
    k4_out<<<ND, H, 0, stream>>>(dsum, dcnt, w_out, b_out, (float*)d_out);
}

// Round 2
// 256.305 us; speedup vs baseline: 2.9511x; 2.9511x over previous
//
#include <hip/hip_runtime.h>

#define H 128
#define ND 4096

// K0: group boundary detection on the sorted group_ids array.
// start[g]/end[g] stay 0 for empty groups (memset), giving len 0.
__global__ void k_bounds(const int* __restrict__ gid,
                         int* __restrict__ start, int* __restrict__ end_, int E) {
    int e = blockIdx.x * blockDim.x + threadIdx.x;
    if (e >= E) return;
    int g = gid[e];
    if (e == 0 || gid[e - 1] != g) start[g] = e;
    if (e == E - 1 || gid[e + 1] != g) end_[g] = e + 1;
}

// K_fused: one wave per group. Online (streaming) softmax over the group's
// entries with chunk-of-4 register-resident rows:
//   - 4 independent gathers in flight (MLP=4)
//   - 4 interleaved butterfly-reduce chains (ILP)
//   - running max m, denom s, accumulator (ax,ay) rescaled per chunk
// One normalized atomic flush per group straight into drug_sum; lane0 bumps
// the per-drug nonempty-group count. Replaces k1+k2+k2b+k3 of round 1:
// ph gathered ONCE (1.02 GB instead of 2.05 GB), no scores/ex arrays,
// no gmax/denom atomics.
__global__ void k_fused(const float* __restrict__ ph,
                        const float* __restrict__ w_attn,
                        const int* __restrict__ prot_idx,
                        const int* __restrict__ start,
                        const int* __restrict__ end_,
                        const int* __restrict__ g2d,
                        float* __restrict__ dsum,
                        int* __restrict__ dcnt, int G) {
    int lane = threadIdx.x & 63;
    int wid  = (blockIdx.x * blockDim.x + threadIdx.x) >> 6;
    int nw   = (gridDim.x * blockDim.x) >> 6;
    float2 wa = *(const float2*)(w_attn + 2 * lane);
    for (int g = wid; g < G; g += nw) {
        int s0 = start[g], s1 = end_[g];
        if (s1 <= s0) continue;
        float m = -INFINITY, s = 0.f;
        float ax = 0.f, ay = 0.f;
        for (int e = s0; e < s1; e += 4) {
            int last = s1 - 1;
            int i1 = min(e + 1, last), i2 = min(e + 2, last), i3 = min(e + 3, last);
            bool b1 = (e + 1 < s1), b2 = (e + 2 < s1), b3 = (e + 3 < s1);
            int p0 = prot_idx[e],  p1 = prot_idx[i1];
            int p2 = prot_idx[i2], p3 = prot_idx[i3];
            float2 v0 = *(const float2*)(ph + (size_t)p0 * H + 2 * lane);
            float2 v1 = *(const float2*)(ph + (size_t)p1 * H + 2 * lane);
            float2 v2 = *(const float2*)(ph + (size_t)p2 * H + 2 * lane);
            float2 v3 = *(const float2*)(ph + (size_t)p3 * H + 2 * lane);
            float d0 = v0.x * wa.x + v0.y * wa.y;
            float d1 = v1.x * wa.x + v1.y * wa.y;
            float d2 = v2.x * wa.x + v2.y * wa.y;
            float d3 = v3.x * wa.x + v3.y * wa.y;
            #pragma unroll
            for (int off = 32; off >= 1; off >>= 1) {
                d0 += __shfl_xor(d0, off, 64);
                d1 += __shfl_xor(d1, off, 64);
                d2 += __shfl_xor(d2, off, 64);
                d3 += __shfl_xor(d3, off, 64);
            }
            if (!b1) d1 = -INFINITY;
            if (!b2) d2 = -INFINITY;
            if (!b3) d3 = -INFINITY;
            float mc = fmaxf(fmaxf(d0, d1), fmaxf(d2, d3));
            float mn = fmaxf(m, mc);              // finite: d0 always valid
            float scale = __expf(m - mn);         // first iter: exp(-inf)=0
            float e0 = __expf(d0 - mn);
            float e1 = __expf(d1 - mn);           // masked lanes: exp(-inf)=0
            float e2 = __expf(d2 - mn);
            float e3 = __expf(d3 - mn);
            s  = s * scale + (e0 + e1) + (e2 + e3);
            ax = ax * scale + e0 * v0.x + e1 * v1.x + e2 * v2.x + e3 * v3.x;
            ay = ay * scale + e0 * v0.y + e1 * v1.y + e2 * v2.y + e3 * v3.y;
            m = mn;
        }
        float inv = 1.0f / s;
        int d = g2d[g];
        atomicAdd(&dsum[(size_t)d * H + 2 * lane],     ax * inv);
        atomicAdd(&dsum[(size_t)d * H + 2 * lane + 1], ay * inv);
        if (lane == 0) atomicAdd(&dcnt[d], 1);
    }
}

// K4: one block (128 threads) per drug. fingerprint row staged in LDS,
// each thread j dots its own w_out row (float4, L2-resident) + bias + ReLU.
__global__ void k4_out(const float* __restrict__ dsum,
                       const int* __restrict__ dcnt,
                       const float* __restrict__ w_out,
                       const float* __restrict__ b_out,
                       float* __restrict__ out) {
    __shared__ float fp[H];
    int d = blockIdx.x;
    int j = threadIdx.x;
    int c = dcnt[d];
    float f = 0.f;
    if (c > 0) f = dsum[(size_t)d * H + j] / (float)c;
    fp[j] = f;
    __syncthreads();
    const float4* wrow = (const float4*)(w_out + (size_t)j * H);
    const float4* fvec = (const float4*)fp;
    float acc = 0.f;
    #pragma unroll
    for (int i = 0; i < H / 4; ++i) {
        float4 w4 = wrow[i];
        float4 f4 = fvec[i];
        acc += w4.x * f4.x + w4.y * f4.y + w4.z * f4.z + w4.w * f4.w;
    }
    acc += b_out[j];
    out[(size_t)d * H + j] = fmaxf(acc, 0.f);
}

extern "C" void kernel_launch(void* const* d_in, const int* in_sizes, int n_in,
                              void* d_out, int out_size, void* d_ws, size_t ws_size,
                              hipStream_t stream) {
    const float* protein_h = (const float*)d_in[0];
    const float* w_attn    = (const float*)d_in[1];
    const float* w_out     = (const float*)d_in[2];
    const float* b_out     = (const float*)d_in[3];
    const int*   prot_idx  = (const int*)d_in[4];
    const int*   group_ids = (const int*)d_in[5];
    const int*   g2d       = (const int*)d_in[6];

    const int E = in_sizes[4];
    const int G = in_sizes[6];

    // Workspace layout (all 4B elems, contiguous so one memset covers all):
    int*   start = (int*)d_ws;                     // G
    int*   end_  = start + G;                      // G
    float* dsum  = (float*)(end_ + G);             // ND*H
    int*   dcnt  = (int*)(dsum + (size_t)ND * H);  // ND

    size_t zbytes = ((size_t)2 * G + (size_t)ND * H + ND) * 4;
    hipMemsetAsync(d_ws, 0, zbytes, stream);

    // K0: group boundaries from sorted group_ids.
    k_bounds<<<(E + 255) / 256, 256, 0, stream>>>(group_ids, start, end_, E);

    // K_fused: one wave per group (4 waves per 256-thread block).
    int blocks = (G + 3) / 4;
    k_fused<<<blocks, 256, 0, stream>>>(protein_h, w_attn, prot_idx,
                                        start, end_, g2d, dsum, dcnt, G);

    // K4: fingerprint + out_proj + ReLU.
    k4_out<<<ND, H, 0, stream>>>(dsum, dcnt, w_out, b_out, (float*)d_out);
}